// Round 6
// baseline (78.141 us; speedup 1.0000x reference)
//
#include <hip/hip_runtime.h>
#include <math.h>

typedef __attribute__((ext_vector_type(8))) __bf16 b16x8;
typedef __attribute__((ext_vector_type(4))) float f32x4;

#define GLDS(gp, lp) __builtin_amdgcn_global_load_lds(                         \
    (const __attribute__((address_space(1))) unsigned int*)(gp),               \
    (__attribute__((address_space(3))) unsigned int*)(lp), 16, 0, 0)

#define WAIT_VM4()   asm volatile("s_waitcnt vmcnt(4)" ::: "memory")
#define WAIT_VM0()   asm volatile("s_waitcnt vmcnt(0)" ::: "memory")
#define BAR()        __builtin_amdgcn_s_barrier()

__device__ __forceinline__ unsigned short f2bf(float x) {
    unsigned int v = __float_as_uint(x);
    v += 0x7fffu + ((v >> 16) & 1u);
    return (unsigned short)(v >> 16);
}

// 16-lane sum reduction entirely on the VALU via DPP (no LDS pipe).
// quad_perm xor1, xor2 -> quad sums; row_half_mirror (^7 == ^4 after quad
// uniform), row_mirror (^15 == ^8 after 8-group uniform).
__device__ __forceinline__ float red16(float x) {
    int v;
    v = __builtin_amdgcn_update_dpp(0, __float_as_int(x), 0xB1, 0xF, 0xF, true);
    x += __int_as_float(v);
    v = __builtin_amdgcn_update_dpp(0, __float_as_int(x), 0x4E, 0xF, 0xF, true);
    x += __int_as_float(v);
    v = __builtin_amdgcn_update_dpp(0, __float_as_int(x), 0x141, 0xF, 0xF, true);
    x += __int_as_float(v);
    v = __builtin_amdgcn_update_dpp(0, __float_as_int(x), 0x140, 0xF, 0xF, true);
    x += __int_as_float(v);
    return x;
}

// ---------------- repack kernel ----------------
// ws layout: [0, 819200): weights bf16, natural tap order (tap = kh*5+kw):
//   idx = ((tap*2 + ks)*256 + o)*32 + cgp*8 + j     (ushort index)
//   stored cin = ks*32 + (cgp ^ ((o>>1)&3))*8 + j   (XOR swizzle for LDS banks)
// [819200, 820224): bias_sum fp32 [256]
__global__ __launch_bounds__(256) void repack_w(
    const float* __restrict__ Wt, const float* __restrict__ bias,
    unsigned short* __restrict__ wsw, float* __restrict__ wsb) {
    int idx = blockIdx.x * 256 + threadIdx.x;
    if (idx < 409600) {
        int j    = idx & 7;
        int cgp  = (idx >> 3) & 3;
        int o    = (idx >> 5) & 255;
        int ks   = (idx >> 13) & 1;
        int tap  = idx >> 14;          // 0..24 = kh*5+kw
        int cg   = cgp ^ ((o >> 1) & 3);
        int cin  = ks * 32 + cg * 8 + j;
        int ic = cin >> 4, id = cin & 15;
        float w = Wt[((size_t)(ic * 256 + o) * 16 + id) * 25 + tap];
        wsw[idx] = f2bf(w);
    } else if (idx < 409856) {
        int o = idx - 409600;
        float s = 0.f;
        for (int ic = 0; ic < 4; ++ic) s += bias[ic * 256 + o];
        wsb[o] = s;
    }
}

// ---------------- main kernel ----------------
// Block: one 16x16 spatial tile x all 256 outputs, 512 threads (8 waves).
// Wave tile: 128 pixels x 64 outputs = 8 pixfrags x 4 ofrags (16x16x32 MFMA).
// Software-pipelined: tap t's B-frags and first A-frags are register-resident
// BEFORE tap t starts (prefetched during tap t-1's MFMA clusters). Cluster 0
// runs pre-barrier from registers; remaining LDS reads hide under clusters.
// Weights: 3 LDS buffers, depth-3 GLDS issue (slot t+3 staged post-BAR at tap
// t), counted vmcnt(4) per tap -> slot t+1 resident in LDS at BAR_t.
__global__ __launch_bounds__(512, 2) void caps_mfma(
    const float* __restrict__ u, const unsigned short* __restrict__ wsw,
    const float* __restrict__ wsb, float* __restrict__ out) {

    __shared__ __align__(16) unsigned short su_sh[25600];       // 2 planes x [hy20][hx20][cgp4][j8]
    __shared__ __align__(16) unsigned short sw_sh[3][16384];    // 3 x [ks2][o256][cgp4][j8]

    const int tid  = threadIdx.x;
    const int lane = tid & 63;
    const int wid  = tid >> 6;
    const int wm   = wid >> 2;      // 0..1  pixel-row-group
    const int wn   = wid & 3;       // 0..3  output-col-group
    const int col  = lane & 15;
    const int cg   = lane >> 4;     // 0..3  cin-group (and x-group in C layout)
    const int ybase = wm * 8;
    const int obase = wn * 64;

    const int bx  = blockIdx.x;     // 0..63
    const int b   = blockIdx.y;     // 0..3
    const int ty0 = (bx >> 3) * 16;
    const int tx0 = (bx & 7) * 16;

    // B-frag element offsets (ushorts) within one weight plane
    int b_elem[4];
    #pragma unroll
    for (int fr = 0; fr < 4; ++fr) {
        int o = obase + fr * 16 + col;
        int cgp = cg ^ ((o >> 1) & 3);
        b_elem[fr] = o * 32 + cgp * 8;
    }

    f32x4 acc[8][4];
    #pragma unroll
    for (int f = 0; f < 8; ++f)
        #pragma unroll
        for (int fr = 0; fr < 4; ++fr) acc[f][fr] = (f32x4)0.f;

    auto stage_u = [&](int half) {
        const float* up = u + ((size_t)b * 64 + half * 32) * 16384;
        unsigned short* dstp = su_sh + half * 12800;
        #pragma unroll 1
        for (int i = tid; i < 12800; i += 512) {
            int c = i / 400;                    // cin local 0..31
            int s = i - c * 400;
            int hy = s / 20, hx = s - hy * 20;  // halo coords 0..19
            int gy = ty0 - 2 + hy, gx = tx0 - 2 + hx;
            float v = 0.f;
            if ((unsigned)gy < 128u && (unsigned)gx < 128u)
                v = up[(size_t)c * 16384 + gy * 128 + gx];
            int cgp = (c >> 3) ^ ((hx >> 1) & 3);
            dstp[(hy * 20 + hx) * 32 + cgp * 8 + (c & 7)] = f2bf(v);
        }
    };

    const char* wbase = ((const char*)wsw) + wid * 4096 + lane * 16;

    auto stage_w = [&](int slot, int bufI) {
        const char* src = wbase + (size_t)slot * 32768;
        char* dst = ((char*)sw_sh) + bufI * 32768 + wid * 4096;   // wave-uniform dest
        GLDS(src,        dst);
        GLDS(src + 1024, dst + 1024);
        GLDS(src + 2048, dst + 2048);
        GLDS(src + 3072, dst + 3072);
    };

    // prologue: stage full u halo and weight slots 0,1,2
    stage_u(0);
    stage_u(1);
    stage_w(0, 0);
    stage_w(1, 1);
    stage_w(2, 2);
    __syncthreads();

    // initial pipeline state: tap 0's B-frags + first A-frags in registers
    b16x8 bfA[8], a0c[4];
    {
        const unsigned short* swb = sw_sh[0];
        #pragma unroll
        for (int fr = 0; fr < 4; ++fr) {
            bfA[fr]     = *reinterpret_cast<const b16x8*>(swb + b_elem[fr]);
            bfA[4 + fr] = *reinterpret_cast<const b16x8*>(swb + 8192 + b_elem[fr]);
        }
        const int coff0 = col * 32 + ((cg ^ ((col >> 1) & 3)) * 8);
        const unsigned short* ap = su_sh + ybase * 640 + coff0;
        #pragma unroll
        for (int f = 0; f < 4; ++f)
            a0c[f] = *reinterpret_cast<const b16x8*>(ap + f * 640);
    }

    int kh = 0, kw = 0, bw = 0, bn = 1;
    #pragma unroll 1
    for (int t = 0; t < 25; ++t) {
        // ---- cluster 0 (pre-barrier, registers only): plane0, f=0..3 ----
        __builtin_amdgcn_s_setprio(1);
        #pragma unroll
        for (int f = 0; f < 4; ++f)
            #pragma unroll
            for (int fr = 0; fr < 4; ++fr)
                acc[f][fr] = __builtin_amdgcn_mfma_f32_16x16x32_bf16(
                    a0c[f], bfA[fr], acc[f][fr], 0, 0, 0);
        __builtin_amdgcn_s_setprio(0);

        BAR();                                // slot t+1 resident; buf[bw] free
        if (t < 22) stage_w(t + 3, bw);       // 4 GLDS, post-barrier (safety)

        const int hx   = col + kw;
        const int coff = hx * 32 + ((cg ^ ((hx >> 1) & 3)) * 8);
        const unsigned short* rp0 = su_sh + (ybase + kh) * 640 + coff;
        const unsigned short* rp1 = rp0 + 12800;

        __builtin_amdgcn_s_setprio(1);
        // ---- cluster 1: plane0, f=4..7 ----
        b16x8 a1[4];
        #pragma unroll
        for (int f = 0; f < 4; ++f)
            a1[f] = *reinterpret_cast<const b16x8*>(rp0 + (f + 4) * 640);
        #pragma unroll
        for (int f = 0; f < 4; ++f)
            #pragma unroll
            for (int fr = 0; fr < 4; ++fr)
                acc[f + 4][fr] = __builtin_amdgcn_mfma_f32_16x16x32_bf16(
                    a1[f], bfA[fr], acc[f + 4][fr], 0, 0, 0);
        // ---- cluster 2: plane1, f=0..3 ----
        b16x8 a2[4];
        #pragma unroll
        for (int f = 0; f < 4; ++f)
            a2[f] = *reinterpret_cast<const b16x8*>(rp1 + f * 640);
        #pragma unroll
        for (int f = 0; f < 4; ++f)
            #pragma unroll
            for (int fr = 0; fr < 4; ++fr)
                acc[f][fr] = __builtin_amdgcn_mfma_f32_16x16x32_bf16(
                    a2[f], bfA[4 + fr], acc[f][fr], 0, 0, 0);
        // ---- cluster 3: plane1, f=4..7 ----
        b16x8 a3[4];
        #pragma unroll
        for (int f = 0; f < 4; ++f)
            a3[f] = *reinterpret_cast<const b16x8*>(rp1 + (f + 4) * 640);
        #pragma unroll
        for (int f = 0; f < 4; ++f)
            #pragma unroll
            for (int fr = 0; fr < 4; ++fr)
                acc[f + 4][fr] = __builtin_amdgcn_mfma_f32_16x16x32_bf16(
                    a3[f], bfA[4 + fr], acc[f + 4][fr], 0, 0, 0);
        __builtin_amdgcn_s_setprio(0);

        // ---- register-prefetch tap t+1 state (hides under clusters) ----
        if (t < 24) {
            const unsigned short* swb = sw_sh[bn];
            #pragma unroll
            for (int fr = 0; fr < 4; ++fr) {
                bfA[fr]     = *reinterpret_cast<const b16x8*>(swb + b_elem[fr]);
                bfA[4 + fr] = *reinterpret_cast<const b16x8*>(swb + 8192 + b_elem[fr]);
            }
            const int kwn = (kw == 4) ? 0 : kw + 1;
            const int khn = (kw == 4) ? kh + 1 : kh;
            const int hxn = col + kwn;
            const int coffn = hxn * 32 + ((cg ^ ((hxn >> 1) & 3)) * 8);
            const unsigned short* apn = su_sh + (ybase + khn) * 640 + coffn;
            #pragma unroll
            for (int f = 0; f < 4; ++f)
                a0c[f] = *reinterpret_cast<const b16x8*>(apn + f * 640);
            kw = kwn; kh = khn;
        }

        WAIT_VM4();                            // slot t+2 landed; t+3 in flight
        bw = (bw == 2) ? 0 : bw + 1;
        bn = (bn == 2) ? 0 : bn + 1;
    }
    WAIT_VM0();   // drain trailing GLDS before LDS lifetime ends

    // ---------------- epilogue: bias + r-scale + squash (DPP) + float4 store --
    float bsv[4];
    #pragma unroll
    for (int fr = 0; fr < 4; ++fr) bsv[fr] = wsb[obase + fr * 16 + col];

    const int xg = lane >> 4;   // x-group in C layout
    #pragma unroll
    for (int f = 0; f < 8; ++f) {
        int h = ty0 + ybase + f;
        int rows = min(h + 2, 127) - max(h - 2, 0) + 1;
        #pragma unroll
        for (int p = 0; p < 2; ++p) {
            int oc = wn * 2 + p;
            float o0[4], o1[4];
            #pragma unroll
            for (int r = 0; r < 4; ++r) {
                int w = tx0 + xg * 4 + r;
                int colsv = min(w + 2, 127) - max(w - 2, 0) + 1;
                float rs = 1.0f / (8.0f * (float)(rows * colsv));
                float p0 = (acc[f][2 * p][r] + bsv[2 * p]) * rs;
                float p1 = (acc[f][2 * p + 1][r] + bsv[2 * p + 1]) * rs;
                o0[r] = p0; o1[r] = p1;
                float sv = red16(p0 * p0 + p1 * p1);
                float scale = sv / ((1.0f + sv) * sqrtf(sv + 1e-9f));
                o0[r] *= scale; o1[r] *= scale;
            }
            size_t base = ((size_t)((b * 8 + oc) * 32) + col) * 16384
                          + (size_t)h * 128 + tx0 + xg * 4;
            float4 v0 = make_float4(o0[0], o0[1], o0[2], o0[3]);
            float4 v1 = make_float4(o1[0], o1[1], o1[2], o1[3]);
            *reinterpret_cast<float4*>(out + base) = v0;
            *reinterpret_cast<float4*>(out + base + (size_t)16 * 16384) = v1;
        }
    }
}

extern "C" void kernel_launch(void* const* d_in, const int* in_sizes, int n_in,
                              void* d_out, int out_size, void* d_ws, size_t ws_size,
                              hipStream_t stream) {
    const float* u    = (const float*)d_in[0];
    const float* Wt   = (const float*)d_in[1];
    const float* bias = (const float*)d_in[2];
    unsigned short* wsw = (unsigned short*)d_ws;
    float* wsb = (float*)((char*)d_ws + 819200);

    repack_w<<<1601, 256, 0, stream>>>(Wt, bias, wsw, wsb);
    caps_mfma<<<dim3(64, 4), 512, 0, stream>>>(u, wsw, wsb, (float*)d_out);
}